// Round 8
// baseline (192.842 us; speedup 1.0000x reference)
//
#include <hip/hip_runtime.h>

typedef unsigned short u16;
typedef unsigned int u32;
typedef __attribute__((ext_vector_type(8))) short bf16x8;
typedef __attribute__((ext_vector_type(4))) short bf16x4v;
typedef __attribute__((ext_vector_type(4))) float f32x4;

#define NWAYS 10
#define NC 128
#define NHW 1024

__device__ __forceinline__ u16 f2bf(float f) {
  u32 u = __builtin_bit_cast(u32, f);
  return (u16)((u + 0x7fffu + ((u >> 16) & 1u)) >> 16);  // RNE
}
__device__ __forceinline__ float bf2f(u16 h) {
  u32 u = ((u32)h) << 16;
  return __builtin_bit_cast(float, u);
}

// ---------------- Kernel 1: direct bf16 cov (no partials) + weighted q-Gram ----------------
// blocks 0..79   : j = bid/8, rg = bid%8 -> covb rows rg*16..rg*16+15 of class j,
//                  full K=5120 streamed in 20 LDS chunks, f32 MFMA accumulation,
//                  all-128 rowsums kept in LDS -> mean correction applied locally.
// blocks 80..335 : Wrawb[qr*64+b] = bf16 sum_p w_p q_c q_d over 256-p quarter ; ss = sum q_c^2
// block = 512 threads (8 waves); LDS 64.5 KiB
__global__ __launch_bounds__(512) void k_phase1(const float* __restrict__ sup,
                                                const float* __restrict__ q,
                                                const float* __restrict__ cw,
                                                u16* __restrict__ covb,
                                                u16* __restrict__ Wrawb,
                                                float* __restrict__ ss,
                                                float* __restrict__ out) {
  __shared__ u16 smem[NC * 256];  // 64 KiB
  __shared__ float saux[NC];
  int bid = blockIdx.x;
  int t = threadIdx.x;
  int w = t >> 6, l = t & 63, lr = l & 15, lg = l >> 4;

  if (bid < 80) {
    // ---- direct covariance: class j, output rows rg*16.. ----
    int j = bid >> 3, rg = bid & 7;
    const float* clsbase = sup + ((size_t)(j * 5) * NC) * NHW;
    if (t < NC) saux[t] = 0.f;  // rowsum accumulator (all 128 rows)
    __syncthreads();

    f32x4 acc;  // one 16x16 tile per wave: rows rg*16.., cols w*16..
    acc = (f32x4){0.f, 0.f, 0.f, 0.f};
#pragma unroll 1
    for (int chunk = 0; chunk < 20; ++chunk) {
      int shot = chunk >> 2, p0 = (chunk & 3) * 256;
      const float* srcbase = clsbase + (size_t)shot * NC * NHW + p0;
#pragma unroll 4
      for (int it = 0; it < 16; ++it) {
        int c = it * 8 + w;  // wave w loads full row c (64 lanes x float4)
        int pos = l;
        float4 v = *(const float4*)(srcbase + (size_t)c * NHW + pos * 4);
        int nl = pos * 4;
        int idx = c * 256 + (((nl >> 3) ^ (c & 15)) << 3) + (nl & 7);
        bf16x4v h;
        h[0] = (short)f2bf(v.x); h[1] = (short)f2bf(v.y);
        h[2] = (short)f2bf(v.z); h[3] = (short)f2bf(v.w);
        *(bf16x4v*)&smem[idx] = h;
        float s = v.x + v.y + v.z + v.w;
#pragma unroll
        for (int m = 1; m <= 32; m <<= 1) s += __shfl_xor(s, m, 64);
        if (l == 0) saux[c] += s;  // unique writer per row, serial over chunks
      }
      __syncthreads();
#pragma unroll
      for (int kb = 0; kb < 8; ++kb) {
        int nn = kb * 32 + lg * 8;
        int arow = rg * 16 + lr;
        int brow = w * 16 + lr;
        bf16x8 fa = *(const bf16x8*)&smem[arow * 256 + (((nn >> 3) ^ (arow & 15)) << 3)];
        bf16x8 fb = *(const bf16x8*)&smem[brow * 256 + (((nn >> 3) ^ (brow & 15)) << 3)];
        acc = __builtin_amdgcn_mfma_f32_16x16x32_bf16(fa, fb, acc, 0, 0, 0);
      }
      __syncthreads();  // MFMA reads done before next chunk overwrites smem
    }
    // epilogue: mean-correct + bf16 store. msd in saux (full 128).
    u16* cj = covb + ((size_t)j << 14);
#pragma unroll
    for (int r = 0; r < 4; ++r) {
      int cr = rg * 16 + lg * 4 + r;  // C/D: row=(lane>>4)*4+reg
      int d = w * 16 + lr;            //      col=lane&15
      cj[cr * NC + d] = f2bf((acc[r] - saux[cr] * saux[d] * (1.0f / 5120.0f)) * (1.0f / 5119.0f));
    }
  } else {
    // ---- weighted q-Gram over one 256-p quarter ----
    int bid2 = bid - 80;
    if (bid2 < 2) {  // zero out (640 floats) for k_wndot's atomics
      int o = bid2 * 512 + t;
      if (o < 64 * NWAYS) out[o] = 0.f;
    }
    int b = bid2 >> 2, qr = bid2 & 3;
    u16* traw = smem;          // [c][128p] swizzled
    u16* twgt = smem + 16384;  // w_p-scaled
    const float* base = q + (size_t)b * NC * NHW + qr * 256;
    const float* cwb = cw + qr * 256;

    float4 v[8];
    auto load_chunk = [&](int chunk) {
#pragma unroll
      for (int it = 0; it < 8; ++it) {
        int idx = it * 512 + t;
        int c = idx >> 5, pos = idx & 31;
        v[it] = *(const float4*)(base + (size_t)c * NHW + chunk * 128 + pos * 4);
      }
    };
    auto store_chunk = [&](int chunk) {
#pragma unroll
      for (int it = 0; it < 8; ++it) {
        int idx = it * 512 + t;
        int c = idx >> 5, pos = idx & 31;
        float4 vv = v[it];
        float4 wv = *(const float4*)(cwb + chunk * 128 + pos * 4);
        int nl = pos * 4;
        int off = c * 128 + (((nl >> 3) ^ (c & 15)) << 3) + (nl & 7);
        bf16x4v hr, hw;
        hr[0] = (short)f2bf(vv.x); hr[1] = (short)f2bf(vv.y);
        hr[2] = (short)f2bf(vv.z); hr[3] = (short)f2bf(vv.w);
        hw[0] = (short)f2bf(vv.x * wv.x); hw[1] = (short)f2bf(vv.y * wv.y);
        hw[2] = (short)f2bf(vv.z * wv.z); hw[3] = (short)f2bf(vv.w * wv.w);
        *(bf16x4v*)&traw[off] = hr;
        *(bf16x4v*)&twgt[off] = hw;
        float s = vv.x * vv.x + vv.y * vv.y + vv.z * vv.z + vv.w * vv.w;
#pragma unroll
        for (int m = 1; m <= 16; m <<= 1) s += __shfl_xor(s, m, 64);
        if ((l & 31) == 0) saux[c] += s;  // unique writer per (chunk,c)
      }
    };

    load_chunk(0);
    if (t < NC) saux[t] = 0.f;
    __syncthreads();  // init visible before any +=
    store_chunk(0);
    __syncthreads();

    f32x4 acc[8];
#pragma unroll
    for (int bt = 0; bt < 8; ++bt) acc[bt] = (f32x4){0.f, 0.f, 0.f, 0.f};
#pragma unroll 1
    for (int chunk = 0; chunk < 2; ++chunk) {
      if (chunk < 1) load_chunk(1);  // issue-early: HBM hides under MFMA
#pragma unroll
      for (int kb = 0; kb < 4; ++kb) {
        int nn = kb * 32 + lg * 8;
        int arow = w * 16 + lr;
        bf16x8 fa = *(const bf16x8*)&twgt[arow * 128 + (((nn >> 3) ^ (arow & 15)) << 3)];
        bf16x8 fb[8];
#pragma unroll
        for (int bt = 0; bt < 8; ++bt) {
          int drow = bt * 16 + lr;
          fb[bt] = *(const bf16x8*)&traw[drow * 128 + (((nn >> 3) ^ (drow & 15)) << 3)];
        }
#pragma unroll
        for (int bt = 0; bt < 8; ++bt)
          acc[bt] = __builtin_amdgcn_mfma_f32_16x16x32_bf16(fa, fb[bt], acc[bt], 0, 0, 0);
      }
      __syncthreads();
      if (chunk < 1) { store_chunk(1); __syncthreads(); }
    }

    if (t < NC) ss[(size_t)(qr * 64 + b) * NC + t] = saux[t];
    u16* wb = Wrawb + ((size_t)(qr * 64 + b) << 14);
#pragma unroll
    for (int bt = 0; bt < 8; ++bt)
#pragma unroll
      for (int r = 0; r < 4; ++r) {
        int cr = w * 16 + lg * 4 + r;
        int d = bt * 16 + lr;
        wb[cr * NC + d] = f2bf(acc[bt][r]);
      }
  }
}

// ---------------- Kernel 2: Wn chunk in registers, dot with all 10 covs ----------------
// grid = 64 b * 4 rowgroups of 32 rows ; block 256 (16 consecutive elems/thread)
__global__ __launch_bounds__(256) void k_wndot(const u16* __restrict__ Wrawb,
                                               const float* __restrict__ ss,
                                               const u16* __restrict__ covb,
                                               float* __restrict__ out) {
  __shared__ float rnl[NC];
  __shared__ float red[4 * NWAYS];
  int b = blockIdx.x >> 2, rg = blockIdx.x & 3;
  int t = threadIdx.x;
  int w = t >> 6, l = t & 63;
  if (t < NC) {
    float s = 0.f;
#pragma unroll
    for (int qr = 0; qr < 4; ++qr) s += ss[(size_t)(qr * 64 + b) * NC + t];
    rnl[t] = rsqrtf(s);
  }
  __syncthreads();
  int e = rg * 4096 + t * 16;  // 32 rows x 128 cols per block
  int c = e >> 7, d0 = e & 127;
  float wn[16];
#pragma unroll
  for (int k = 0; k < 16; ++k) wn[k] = 0.f;
#pragma unroll
  for (int qr = 0; qr < 4; ++qr) {
    const u16* src = Wrawb + (((size_t)(qr * 64 + b)) << 14) + e;
    bf16x8 v0 = *(const bf16x8*)src;
    bf16x8 v1 = *(const bf16x8*)(src + 8);
#pragma unroll
    for (int k = 0; k < 8; ++k) { wn[k] += bf2f((u16)v0[k]); wn[8 + k] += bf2f((u16)v1[k]); }
  }
  float rc = rnl[c];
#pragma unroll
  for (int k = 0; k < 16; ++k) wn[k] *= rc * rnl[d0 + k];

  float acc[NWAYS];
#pragma unroll
  for (int j = 0; j < NWAYS; ++j) {
    const u16* cj = covb + ((size_t)j << 14) + e;
    bf16x8 c0 = *(const bf16x8*)cj;
    bf16x8 c1 = *(const bf16x8*)(cj + 8);
    float s = 0.f;
#pragma unroll
    for (int k = 0; k < 8; ++k) s += wn[k] * bf2f((u16)c0[k]) + wn[8 + k] * bf2f((u16)c1[k]);
    acc[j] = s;
  }
#pragma unroll
  for (int j = 0; j < NWAYS; ++j)
#pragma unroll
    for (int m = 1; m <= 32; m <<= 1) acc[j] += __shfl_xor(acc[j], m, 64);
  if (l == 0)
#pragma unroll
    for (int j = 0; j < NWAYS; ++j) red[w * NWAYS + j] = acc[j];
  __syncthreads();
  if (t < NWAYS)
    atomicAdd(&out[b * NWAYS + t],
              red[t] + red[NWAYS + t] + red[2 * NWAYS + t] + red[3 * NWAYS + t]);
}

extern "C" void kernel_launch(void* const* d_in, const int* in_sizes, int n_in,
                              void* d_out, int out_size, void* d_ws, size_t ws_size,
                              hipStream_t stream) {
  (void)in_sizes; (void)n_in; (void)out_size; (void)ws_size;
  const float* q = (const float*)d_in[0];
  const float* sup = (const float*)d_in[1];
  const float* cw = (const float*)d_in[2];
  float* out = (float*)d_out;

  char* p = (char*)d_ws;
  u16* covb = (u16*)p;   p += (size_t)10 * 16384 * 2;   // 320 KB
  u16* Wrawb = (u16*)p;  p += (size_t)256 * 16384 * 2;  // 8.4 MB
  float* ssb = (float*)p;

  k_phase1<<<336, 512, 0, stream>>>(sup, q, cw, covb, Wrawb, ssb, out);
  k_wndot<<<256, 256, 0, stream>>>(Wrawb, ssb, covb, out);
}

// Round 9
// 137.113 us; speedup vs baseline: 1.4064x; 1.4064x over previous
//
#include <hip/hip_runtime.h>

typedef unsigned short u16;
typedef unsigned int u32;
typedef __attribute__((ext_vector_type(8))) short bf16x8;
typedef __attribute__((ext_vector_type(4))) short bf16x4v;
typedef __attribute__((ext_vector_type(4))) float f32x4;

#define NWAYS 10
#define NC 128
#define NHW 1024
#define NBLK 456

__device__ __forceinline__ u16 f2bf(float f) {
  u32 u = __builtin_bit_cast(u32, f);
  return (u16)((u + 0x7fffu + ((u >> 16) & 1u)) >> 16);  // RNE
}
__device__ __forceinline__ float bf2f(u16 h) {
  u32 u = ((u32)h) << 16;
  return __builtin_bit_cast(float, u);
}

// Poison/replay-proof grid barrier: monotonic counter, base read at kernel entry,
// wrap-safe unsigned compare. All NBLK blocks are co-resident (2 blocks/CU, 456<=512).
__device__ __forceinline__ void grid_barrier(u32* cnt, u32 base, int t) {
  __syncthreads();
  if (t == 0) {
    __threadfence();                 // release: our global writes visible
    atomicAdd(cnt, 1u);
    while ((u32)(atomicAdd(cnt, 0u) - base) < (u32)NBLK) __builtin_amdgcn_s_sleep(8);
    __threadfence();                 // acquire
  }
  __syncthreads();
}

// ---- single kernel, 3 phases, 2 manual grid barriers ----
// grid = 456 x 512 thr; LDS 64.8 KiB -> 2 blocks/CU (all co-resident)
__global__ __launch_bounds__(512, 4) void k_all(const float* __restrict__ sup,
                                                const float* __restrict__ q,
                                                const float* __restrict__ cw,
                                                u16* __restrict__ Gpartb,
                                                float* __restrict__ mpart,
                                                u16* __restrict__ Wrawb,
                                                float* __restrict__ ss,
                                                u16* __restrict__ covb,
                                                float* __restrict__ out,
                                                u32* __restrict__ bar) {
  __shared__ u16 smem[NC * 256];  // 64 KiB
  __shared__ float saux[NC];
  __shared__ float red[8 * NWAYS];
  int bid = blockIdx.x;
  int t = threadIdx.x;
  int w = t >> 6, l = t & 63, lr = l & 15, lg = l >> 4;
  u32 base0 = 0, base1 = 0;
  if (t == 0) {  // entry-read: stable (first arrival is >=5us away, dispatch <1us)
    base0 = atomicAdd(&bar[0], 0u);
    base1 = atomicAdd(&bar[1], 0u);
  }

  // ================= Phase 1: support-Gram partials + weighted q-Gram =================
  if (bid < 200) {
    // ---- covariance Gram over one 256-n chunk ----
    int j = bid / 20, chunk = bid % 20;
    int shot = chunk >> 2, p0 = (chunk & 3) * 256;
    const float* srcbase = sup + ((size_t)(j * 5 + shot) * NC) * NHW + p0;
#pragma unroll 4
    for (int it = 0; it < 16; ++it) {
      int c = it * 8 + w;
      int pos = t & 63;
      float4 v = *(const float4*)(srcbase + (size_t)c * NHW + pos * 4);
      int nl = pos * 4;
      int idx = c * 256 + (((nl >> 3) ^ (c & 15)) << 3) + (nl & 7);
      bf16x4v h;
      h[0] = (short)f2bf(v.x); h[1] = (short)f2bf(v.y);
      h[2] = (short)f2bf(v.z); h[3] = (short)f2bf(v.w);
      *(bf16x4v*)&smem[idx] = h;
      float s = v.x + v.y + v.z + v.w;
#pragma unroll
      for (int m = 1; m <= 32; m <<= 1) s += __shfl_xor(s, m, 64);
      if (l == 0) saux[c] = s;  // wave-uniform c, unique per (it,w)
    }
    __syncthreads();
    if (t < NC) mpart[(size_t)bid * NC + t] = saux[t];

    f32x4 acc[8];
#pragma unroll
    for (int bt = 0; bt < 8; ++bt) acc[bt] = (f32x4){0.f, 0.f, 0.f, 0.f};
#pragma unroll 1
    for (int kb = 0; kb < 8; ++kb) {
      int nn = kb * 32 + lg * 8;
      int arow = w * 16 + lr;  // 8 waves x 16 rows = 128
      bf16x8 fa = *(const bf16x8*)&smem[arow * 256 + (((nn >> 3) ^ (arow & 15)) << 3)];
      bf16x8 fb[8];
#pragma unroll
      for (int bt = 0; bt < 8; ++bt) {
        int drow = bt * 16 + lr;
        fb[bt] = *(const bf16x8*)&smem[drow * 256 + (((nn >> 3) ^ (drow & 15)) << 3)];
      }
#pragma unroll
      for (int bt = 0; bt < 8; ++bt)
        acc[bt] = __builtin_amdgcn_mfma_f32_16x16x32_bf16(fa, fb[bt], acc[bt], 0, 0, 0);
    }
    u16* gp = Gpartb + ((size_t)bid << 14);
#pragma unroll
    for (int bt = 0; bt < 8; ++bt)
#pragma unroll
      for (int r = 0; r < 4; ++r) {
        int cr = w * 16 + lg * 4 + r;  // C/D: row=(lane>>4)*4+reg
        int d = bt * 16 + lr;          //      col=lane&15
        gp[cr * NC + d] = f2bf(acc[bt][r]);
      }
  } else {
    // ---- weighted q-Gram over one 256-p quarter ----
    int bid2 = bid - 200;
    int b = bid2 >> 2, qr = bid2 & 3;
    u16* traw = smem;          // [c][128p] swizzled
    u16* twgt = smem + 16384;  // w_p-scaled
    const float* base = q + (size_t)b * NC * NHW + qr * 256;
    const float* cwb = cw + qr * 256;

    float4 v[8];
    auto load_chunk = [&](int chunk) {
#pragma unroll
      for (int it = 0; it < 8; ++it) {
        int idx = it * 512 + t;
        int c = idx >> 5, pos = idx & 31;
        v[it] = *(const float4*)(base + (size_t)c * NHW + chunk * 128 + pos * 4);
      }
    };
    auto store_chunk = [&](int chunk) {
#pragma unroll
      for (int it = 0; it < 8; ++it) {
        int idx = it * 512 + t;
        int c = idx >> 5, pos = idx & 31;
        float4 vv = v[it];
        float4 wv = *(const float4*)(cwb + chunk * 128 + pos * 4);
        int nl = pos * 4;
        int off = c * 128 + (((nl >> 3) ^ (c & 15)) << 3) + (nl & 7);
        bf16x4v hr, hw;
        hr[0] = (short)f2bf(vv.x); hr[1] = (short)f2bf(vv.y);
        hr[2] = (short)f2bf(vv.z); hr[3] = (short)f2bf(vv.w);
        hw[0] = (short)f2bf(vv.x * wv.x); hw[1] = (short)f2bf(vv.y * wv.y);
        hw[2] = (short)f2bf(vv.z * wv.z); hw[3] = (short)f2bf(vv.w * wv.w);
        *(bf16x4v*)&traw[off] = hr;
        *(bf16x4v*)&twgt[off] = hw;
        float s = vv.x * vv.x + vv.y * vv.y + vv.z * vv.z + vv.w * vv.w;
#pragma unroll
        for (int m = 1; m <= 16; m <<= 1) s += __shfl_xor(s, m, 64);
        if ((l & 31) == 0) saux[c] += s;  // unique writer per (chunk,c)
      }
    };

    load_chunk(0);
    if (t < NC) saux[t] = 0.f;
    __syncthreads();  // init visible before any +=
    store_chunk(0);
    __syncthreads();

    f32x4 acc[8];
#pragma unroll
    for (int bt = 0; bt < 8; ++bt) acc[bt] = (f32x4){0.f, 0.f, 0.f, 0.f};
#pragma unroll 1
    for (int chunk = 0; chunk < 2; ++chunk) {
      if (chunk < 1) load_chunk(1);  // issue-early: HBM hides under MFMA
#pragma unroll
      for (int kb = 0; kb < 4; ++kb) {
        int nn = kb * 32 + lg * 8;
        int arow = w * 16 + lr;
        bf16x8 fa = *(const bf16x8*)&twgt[arow * 128 + (((nn >> 3) ^ (arow & 15)) << 3)];
        bf16x8 fb[8];
#pragma unroll
        for (int bt = 0; bt < 8; ++bt) {
          int drow = bt * 16 + lr;
          fb[bt] = *(const bf16x8*)&traw[drow * 128 + (((nn >> 3) ^ (drow & 15)) << 3)];
        }
#pragma unroll
        for (int bt = 0; bt < 8; ++bt)
          acc[bt] = __builtin_amdgcn_mfma_f32_16x16x32_bf16(fa, fb[bt], acc[bt], 0, 0, 0);
      }
      __syncthreads();
      if (chunk < 1) { store_chunk(1); __syncthreads(); }
    }

    if (t < NC) ss[(size_t)(qr * 64 + b) * NC + t] = saux[t];
    u16* wb = Wrawb + ((size_t)(qr * 64 + b) << 14);
#pragma unroll
    for (int bt = 0; bt < 8; ++bt)
#pragma unroll
      for (int r = 0; r < 4; ++r) {
        int cr = w * 16 + lg * 4 + r;
        int d = bt * 16 + lr;
        wb[cr * NC + d] = f2bf(acc[bt][r]);
      }
  }

  grid_barrier(&bar[0], base0, t);

  // ================= Phase 2: reduce Gram partials -> bf16 cov =================
  // 80 blocks: (j, sub of 8) ; 512 thr x 4 consecutive d
  if (bid < 80) {
    int j = bid >> 3, sub = bid & 7;
    if (t < NC) {
      float s = 0.f;
#pragma unroll
      for (int k = 0; k < 20; ++k) s += mpart[(size_t)(j * 20 + k) * NC + t];
      saux[t] = s;
    }
    __syncthreads();
    int e = sub * 2048 + t * 4;  // 16 rows x 128 cols per block
    int c = e >> 7, d0 = e & 127;
    float g[4] = {0.f, 0.f, 0.f, 0.f};
#pragma unroll
    for (int k = 0; k < 20; ++k) {
      bf16x4v v = *(const bf16x4v*)(Gpartb + (((size_t)(j * 20 + k)) << 14) + e);
#pragma unroll
      for (int r = 0; r < 4; ++r) g[r] += bf2f((u16)v[r]);
    }
    bf16x4v o;
#pragma unroll
    for (int r = 0; r < 4; ++r)
      o[r] = (short)f2bf((g[r] - saux[c] * saux[d0 + r] * (1.0f / 5120.0f)) * (1.0f / 5119.0f));
    *(bf16x4v*)(covb + (((size_t)j) << 14) + e) = o;
  }

  grid_barrier(&bar[1], base1, t);

  // ================= Phase 3: Wn in registers, dot with all 10 covs =================
  // 64 blocks (one per b); 512 thr x 32 consecutive elems; plain store to out
  if (bid < 64) {
    int b = bid;
    if (t < NC) {
      float s = 0.f;
#pragma unroll
      for (int qr = 0; qr < 4; ++qr) s += ss[(size_t)(qr * 64 + b) * NC + t];
      saux[t] = rsqrtf(s);
    }
    __syncthreads();
    int e = t * 32;
    int c = e >> 7, d0 = e & 127;
    float wn[32];
#pragma unroll
    for (int k = 0; k < 32; ++k) wn[k] = 0.f;
#pragma unroll
    for (int qr = 0; qr < 4; ++qr) {
      const u16* src = Wrawb + (((size_t)(qr * 64 + b)) << 14) + e;
#pragma unroll
      for (int h = 0; h < 4; ++h) {
        bf16x8 v8 = *(const bf16x8*)(src + h * 8);
#pragma unroll
        for (int k = 0; k < 8; ++k) wn[h * 8 + k] += bf2f((u16)v8[k]);
      }
    }
    float rc = saux[c];
#pragma unroll
    for (int k = 0; k < 32; ++k) wn[k] *= rc * saux[d0 + k];

    float acc[NWAYS];
#pragma unroll
    for (int j = 0; j < NWAYS; ++j) {
      const u16* cj = covb + ((size_t)j << 14) + e;
      float s = 0.f;
#pragma unroll
      for (int h = 0; h < 4; ++h) {
        bf16x8 c8 = *(const bf16x8*)(cj + h * 8);
#pragma unroll
        for (int k = 0; k < 8; ++k) s += wn[h * 8 + k] * bf2f((u16)c8[k]);
      }
      acc[j] = s;
    }
#pragma unroll
    for (int j = 0; j < NWAYS; ++j)
#pragma unroll
      for (int m = 1; m <= 32; m <<= 1) acc[j] += __shfl_xor(acc[j], m, 64);
    if (l == 0)
#pragma unroll
      for (int j = 0; j < NWAYS; ++j) red[w * NWAYS + j] = acc[j];
    __syncthreads();
    if (t < NWAYS) {
      float s = 0.f;
#pragma unroll
      for (int wv = 0; wv < 8; ++wv) s += red[wv * NWAYS + t];
      out[b * NWAYS + t] = s;
    }
  }
}

extern "C" void kernel_launch(void* const* d_in, const int* in_sizes, int n_in,
                              void* d_out, int out_size, void* d_ws, size_t ws_size,
                              hipStream_t stream) {
  (void)in_sizes; (void)n_in; (void)out_size; (void)ws_size;
  const float* q = (const float*)d_in[0];
  const float* sup = (const float*)d_in[1];
  const float* cw = (const float*)d_in[2];
  float* out = (float*)d_out;

  char* p = (char*)d_ws;
  u16* Gpartb = (u16*)p;    p += (size_t)200 * 16384 * 2;  // 6.55 MB
  float* mpart = (float*)p; p += (size_t)200 * 128 * 4;
  u16* covb = (u16*)p;      p += (size_t)10 * 16384 * 2;
  u16* Wrawb = (u16*)p;     p += (size_t)256 * 16384 * 2;  // 8.4 MB
  float* ssb = (float*)p;   p += (size_t)256 * 128 * 4;
  u32* bar = (u32*)p;       // 2 monotonic barrier counters (poison-proof protocol)

  k_all<<<NBLK, 512, 0, stream>>>(sup, q, cw, Gpartb, mpart, Wrawb, ssb, covb, out, bar);
}

// Round 11
// 49.203 us; speedup vs baseline: 3.9193x; 2.7867x over previous
//
#include <hip/hip_runtime.h>

typedef unsigned short u16;
typedef unsigned int u32;
typedef __attribute__((ext_vector_type(8))) short bf16x8;
typedef __attribute__((ext_vector_type(4))) short bf16x4v;
typedef __attribute__((ext_vector_type(4))) float f32x4;

#define NWAYS 10
#define NC 128
#define NHW 1024

__device__ __forceinline__ u16 f2bf(float f) {
  u32 u = __builtin_bit_cast(u32, f);
  return (u16)((u + 0x7fffu + ((u >> 16) & 1u)) >> 16);  // RNE
}
__device__ __forceinline__ float bf2f(u16 h) {
  u32 u = ((u32)h) << 16;
  return __builtin_bit_cast(float, u);
}

// ---------------- Kernel 1: fused support-Gram partials + weighted q-Gram ----------------
// blocks 0..199   : Gpartb[j*20+chunk] = bf16 Gram of 256-n support chunk ; mpart f32 rowsums
// blocks 200..455 : Wrawb[qr*64+b] = bf16 sum_p w_p q_c q_d over 256-p quarter ; ss = sum q_c^2
// block = 512 threads (8 waves); LDS 64.5 KiB  [R6-verified body; + out zeroing from R8]
__global__ __launch_bounds__(512) void k_phase1(const float* __restrict__ sup,
                                                const float* __restrict__ q,
                                                const float* __restrict__ cw,
                                                u16* __restrict__ Gpartb,
                                                float* __restrict__ mpart,
                                                u16* __restrict__ Wrawb,
                                                float* __restrict__ ss,
                                                float* __restrict__ out) {
  __shared__ u16 smem[NC * 256];  // 64 KiB
  __shared__ float saux[NC];
  int bid = blockIdx.x;
  int t = threadIdx.x;
  int w = t >> 6, l = t & 63, lr = l & 15, lg = l >> 4;

  if (bid < 200) {
    // ---- covariance Gram over one 256-n chunk ----
    int j = bid / 20, chunk = bid % 20;
    int shot = chunk >> 2, p0 = (chunk & 3) * 256;
    const float* srcbase = sup + ((size_t)(j * 5 + shot) * NC) * NHW + p0;
#pragma unroll 4
    for (int it = 0; it < 16; ++it) {
      int c = it * 8 + w;
      int pos = t & 63;
      float4 v = *(const float4*)(srcbase + (size_t)c * NHW + pos * 4);
      int nl = pos * 4;
      int idx = c * 256 + (((nl >> 3) ^ (c & 15)) << 3) + (nl & 7);
      bf16x4v h;
      h[0] = (short)f2bf(v.x); h[1] = (short)f2bf(v.y);
      h[2] = (short)f2bf(v.z); h[3] = (short)f2bf(v.w);
      *(bf16x4v*)&smem[idx] = h;
      float s = v.x + v.y + v.z + v.w;
#pragma unroll
      for (int m = 1; m <= 32; m <<= 1) s += __shfl_xor(s, m, 64);
      if (l == 0) saux[c] = s;  // wave-uniform c, unique per (it,w)
    }
    __syncthreads();
    if (t < NC) mpart[(size_t)bid * NC + t] = saux[t];

    f32x4 acc[8];
#pragma unroll
    for (int bt = 0; bt < 8; ++bt) acc[bt] = (f32x4){0.f, 0.f, 0.f, 0.f};
#pragma unroll 1
    for (int kb = 0; kb < 8; ++kb) {
      int nn = kb * 32 + lg * 8;
      int arow = w * 16 + lr;  // 8 waves x 16 rows = 128
      bf16x8 fa = *(const bf16x8*)&smem[arow * 256 + (((nn >> 3) ^ (arow & 15)) << 3)];
      bf16x8 fb[8];
#pragma unroll
      for (int bt = 0; bt < 8; ++bt) {
        int drow = bt * 16 + lr;
        fb[bt] = *(const bf16x8*)&smem[drow * 256 + (((nn >> 3) ^ (drow & 15)) << 3)];
      }
#pragma unroll
      for (int bt = 0; bt < 8; ++bt)
        acc[bt] = __builtin_amdgcn_mfma_f32_16x16x32_bf16(fa, fb[bt], acc[bt], 0, 0, 0);
    }
    u16* gp = Gpartb + ((size_t)bid << 14);
#pragma unroll
    for (int bt = 0; bt < 8; ++bt)
#pragma unroll
      for (int r = 0; r < 4; ++r) {
        int cr = w * 16 + lg * 4 + r;  // C/D: row=(lane>>4)*4+reg
        int d = bt * 16 + lr;          //      col=lane&15
        gp[cr * NC + d] = f2bf(acc[bt][r]);
      }
  } else {
    // ---- weighted q-Gram over one 256-p quarter ----
    int bid2 = bid - 200;
    if (bid2 < 2) {  // zero out (640 floats) for k_fin2's atomics (R8-verified)
      int o = bid2 * 512 + t;
      if (o < 64 * NWAYS) out[o] = 0.f;
    }
    int b = bid2 >> 2, qr = bid2 & 3;
    u16* traw = smem;          // [c][128p] swizzled
    u16* twgt = smem + 16384;  // w_p-scaled
    const float* base = q + (size_t)b * NC * NHW + qr * 256;
    const float* cwb = cw + qr * 256;

    float4 v[8];
    auto load_chunk = [&](int chunk) {
#pragma unroll
      for (int it = 0; it < 8; ++it) {
        int idx = it * 512 + t;
        int c = idx >> 5, pos = idx & 31;
        v[it] = *(const float4*)(base + (size_t)c * NHW + chunk * 128 + pos * 4);
      }
    };
    auto store_chunk = [&](int chunk) {
#pragma unroll
      for (int it = 0; it < 8; ++it) {
        int idx = it * 512 + t;
        int c = idx >> 5, pos = idx & 31;
        float4 vv = v[it];
        float4 wv = *(const float4*)(cwb + chunk * 128 + pos * 4);
        int nl = pos * 4;
        int off = c * 128 + (((nl >> 3) ^ (c & 15)) << 3) + (nl & 7);
        bf16x4v hr, hw;
        hr[0] = (short)f2bf(vv.x); hr[1] = (short)f2bf(vv.y);
        hr[2] = (short)f2bf(vv.z); hr[3] = (short)f2bf(vv.w);
        hw[0] = (short)f2bf(vv.x * wv.x); hw[1] = (short)f2bf(vv.y * wv.y);
        hw[2] = (short)f2bf(vv.z * wv.z); hw[3] = (short)f2bf(vv.w * wv.w);
        *(bf16x4v*)&traw[off] = hr;
        *(bf16x4v*)&twgt[off] = hw;
        float s = vv.x * vv.x + vv.y * vv.y + vv.z * vv.z + vv.w * vv.w;
#pragma unroll
        for (int m = 1; m <= 16; m <<= 1) s += __shfl_xor(s, m, 64);
        if ((l & 31) == 0) saux[c] += s;  // unique writer per (chunk,c)
      }
    };

    load_chunk(0);
    if (t < NC) saux[t] = 0.f;
    __syncthreads();  // init visible before any +=
    store_chunk(0);
    __syncthreads();

    f32x4 acc[8];
#pragma unroll
    for (int bt = 0; bt < 8; ++bt) acc[bt] = (f32x4){0.f, 0.f, 0.f, 0.f};
#pragma unroll 1
    for (int chunk = 0; chunk < 2; ++chunk) {
      if (chunk < 1) load_chunk(1);  // issue-early: HBM hides under MFMA
#pragma unroll
      for (int kb = 0; kb < 4; ++kb) {
        int nn = kb * 32 + lg * 8;
        int arow = w * 16 + lr;
        bf16x8 fa = *(const bf16x8*)&twgt[arow * 128 + (((nn >> 3) ^ (arow & 15)) << 3)];
        bf16x8 fb[8];
#pragma unroll
        for (int bt = 0; bt < 8; ++bt) {
          int drow = bt * 16 + lr;
          fb[bt] = *(const bf16x8*)&traw[drow * 128 + (((nn >> 3) ^ (drow & 15)) << 3)];
        }
#pragma unroll
        for (int bt = 0; bt < 8; ++bt)
          acc[bt] = __builtin_amdgcn_mfma_f32_16x16x32_bf16(fa, fb[bt], acc[bt], 0, 0, 0);
      }
      __syncthreads();
      if (chunk < 1) { store_chunk(1); __syncthreads(); }
    }

    if (t < NC) ss[(size_t)(qr * 64 + b) * NC + t] = saux[t];
    u16* wb = Wrawb + ((size_t)(qr * 64 + b) << 14);
#pragma unroll
    for (int bt = 0; bt < 8; ++bt)
#pragma unroll
      for (int r = 0; r < 4; ++r) {
        int cr = w * 16 + lg * 4 + r;
        int d = bt * 16 + lr;
        wb[cr * NC + d] = f2bf(acc[bt][r]);
      }
  }
}

// ---------------- Kernel 2: fused cov-reduce + rn + Wsum dot (no covb tensor) ----------------
// grid = 320: bid = (j*8+sub)*4 + bq ; j class, sub = 16-row cov slice, bq = 16-b group.
// Each block: cov slice in registers (f32), rn for its 16 b's in LDS, dot against
// the 4 Wraw quarters of those b's, atomicAdd 16 partials into out.
__global__ __launch_bounds__(512) void k_fin2(const u16* __restrict__ Gpartb,
                                              const float* __restrict__ mpart,
                                              const u16* __restrict__ Wrawb,
                                              const float* __restrict__ ss,
                                              float* __restrict__ out) {
  __shared__ float msd[NC];
  __shared__ float rnl[16 * NC];  // 8 KiB: rn for 16 b's
  __shared__ float red[8 * 16];   // per-wave partial per local b
  int bid = blockIdx.x;
  int j = bid >> 5, sub = (bid >> 2) & 7, bq = bid & 3;
  int t = threadIdx.x;
  int w = t >> 6, l = t & 63;

  if (t < NC) {  // class mean-sums
    float s = 0.f;
#pragma unroll
    for (int k = 0; k < 20; ++k) s += mpart[(size_t)(j * 20 + k) * NC + t];
    msd[t] = s;
  }
  {  // rn for 16 b's: idx = t*4 over 16x128
    int idx = t * 4;
    int bb = idx >> 7;
    int b = bq * 16 + bb;
    int c0 = idx & 127;
    float4 s4 = (float4){0.f, 0.f, 0.f, 0.f};
#pragma unroll
    for (int qr = 0; qr < 4; ++qr) {
      float4 v = *(const float4*)(ss + (size_t)(qr * 64 + b) * NC + c0);
      s4.x += v.x; s4.y += v.y; s4.z += v.z; s4.w += v.w;
    }
    rnl[idx] = rsqrtf(s4.x); rnl[idx + 1] = rsqrtf(s4.y);
    rnl[idx + 2] = rsqrtf(s4.z); rnl[idx + 3] = rsqrtf(s4.w);
  }
  __syncthreads();

  // cov slice in registers: e = t*4 over 16 rows x 128 cols
  int r = t >> 5, d0 = (t & 31) * 4;
  int c = sub * 16 + r;
  float cv[4];
  {
    float g[4] = {0.f, 0.f, 0.f, 0.f};
#pragma unroll
    for (int k = 0; k < 20; ++k) {
      bf16x4v v = *(const bf16x4v*)(Gpartb + (((size_t)(j * 20 + k)) << 14) + c * NC + d0);
#pragma unroll
      for (int i = 0; i < 4; ++i) g[i] += bf2f((u16)v[i]);
    }
#pragma unroll
    for (int i = 0; i < 4; ++i)
      cv[i] = (g[i] - msd[c] * msd[d0 + i] * (1.0f / 5120.0f)) * (1.0f / 5119.0f);
  }

  // dot against 16 b's
#pragma unroll 1
  for (int bb = 0; bb < 16; ++bb) {
    int b = bq * 16 + bb;
    float rnrow = rnl[bb * NC + c];
    float4 rd = *(const float4*)&rnl[bb * NC + d0];
    float ws[4] = {0.f, 0.f, 0.f, 0.f};
#pragma unroll
    for (int qr = 0; qr < 4; ++qr) {
      bf16x4v wv = *(const bf16x4v*)(Wrawb + (((size_t)(qr * 64 + b)) << 14) + c * NC + d0);
#pragma unroll
      for (int i = 0; i < 4; ++i) ws[i] += bf2f((u16)wv[i]);
    }
    float s = rnrow * (cv[0] * rd.x * ws[0] + cv[1] * rd.y * ws[1] +
                       cv[2] * rd.z * ws[2] + cv[3] * rd.w * ws[3]);
#pragma unroll
    for (int m = 1; m <= 32; m <<= 1) s += __shfl_xor(s, m, 64);
    if (l == 0) red[w * 16 + bb] = s;
  }
  __syncthreads();
  if (t < 16) {
    float s = 0.f;
#pragma unroll
    for (int wv = 0; wv < 8; ++wv) s += red[wv * 16 + t];
    atomicAdd(&out[(bq * 16 + t) * NWAYS + j], s);
  }
}

extern "C" void kernel_launch(void* const* d_in, const int* in_sizes, int n_in,
                              void* d_out, int out_size, void* d_ws, size_t ws_size,
                              hipStream_t stream) {
  (void)in_sizes; (void)n_in; (void)out_size; (void)ws_size;
  const float* q = (const float*)d_in[0];
  const float* sup = (const float*)d_in[1];
  const float* cw = (const float*)d_in[2];
  float* out = (float*)d_out;

  char* p = (char*)d_ws;
  u16* Gpartb = (u16*)p;    p += (size_t)200 * 16384 * 2;  // 6.55 MB
  float* mpart = (float*)p; p += (size_t)200 * 128 * 4;
  u16* Wrawb = (u16*)p;     p += (size_t)256 * 16384 * 2;  // 8.4 MB
  float* ssb = (float*)p;

  k_phase1<<<456, 512, 0, stream>>>(sup, q, cw, Gpartb, mpart, Wrawb, ssb, out);
  k_fin2<<<320, 512, 0, stream>>>(Gpartb, mpart, Wrawb, ssb, out);
}

// Round 12
// 36.063 us; speedup vs baseline: 5.3474x; 1.3644x over previous
//
#include <hip/hip_runtime.h>

typedef unsigned short u16;
typedef unsigned int u32;
typedef __attribute__((ext_vector_type(8))) short bf16x8;
typedef __attribute__((ext_vector_type(4))) short bf16x4v;
typedef __attribute__((ext_vector_type(4))) float f32x4;

#define NWAYS 10
#define NC 128
#define NHW 1024

__device__ __forceinline__ u16 f2bf(float f) {
  u32 u = __builtin_bit_cast(u32, f);
  return (u16)((u + 0x7fffu + ((u >> 16) & 1u)) >> 16);  // RNE
}
__device__ __forceinline__ float bf2f(u16 h) {
  u32 u = ((u32)h) << 16;
  return __builtin_bit_cast(float, u);
}

// ---------------- Kernel 1: fused support-Gram + weighted q-Gram, 512-wide chunks ----------------
// blocks 0..99    : Gpartb[j*10+chunk] = bf16 Gram of a 512-n support chunk (2 staged sub-chunks,
//                   f32 MFMA acc across both) ; mpart[j*10+chunk] = f32 rowsums over 512 n
// blocks 100..227 : Wrawb[half*64+b] = bf16 sum_p w_p q_c q_d over 512-p half (4-chunk pipeline) ;
//                   ss[half*64+b] = sum q_c^2
// block = 512 threads (8 waves); LDS 64.5 KiB
__global__ __launch_bounds__(512) void k_phase1(const float* __restrict__ sup,
                                                const float* __restrict__ q,
                                                const float* __restrict__ cw,
                                                u16* __restrict__ Gpartb,
                                                float* __restrict__ mpart,
                                                u16* __restrict__ Wrawb,
                                                float* __restrict__ ss,
                                                float* __restrict__ out) {
  __shared__ u16 smem[NC * 256];  // 64 KiB
  __shared__ float saux[NC];
  int bid = blockIdx.x;
  int t = threadIdx.x;
  int w = t >> 6, l = t & 63, lr = l & 15, lg = l >> 4;

  if (bid < 100) {
    // ---- covariance Gram over one 512-n chunk (2 sub-chunks of 256) ----
    int j = bid / 10, chunk = bid % 10;
    int shot = chunk >> 1, p0 = (chunk & 1) * 512;
    const float* srcbase = sup + ((size_t)(j * 5 + shot) * NC) * NHW + p0;
    if (t < NC) saux[t] = 0.f;
    __syncthreads();  // init visible before first +=

    f32x4 acc[8];
#pragma unroll
    for (int bt = 0; bt < 8; ++bt) acc[bt] = (f32x4){0.f, 0.f, 0.f, 0.f};

#pragma unroll 1
    for (int sub = 0; sub < 2; ++sub) {
      const float* srcsub = srcbase + sub * 256;
#pragma unroll 4
      for (int it = 0; it < 16; ++it) {
        int c = it * 8 + w;  // wave w stages full row c (64 lanes x float4)
        float4 v = *(const float4*)(srcsub + (size_t)c * NHW + l * 4);
        int nl = l * 4;
        int idx = c * 256 + (((nl >> 3) ^ (c & 15)) << 3) + (nl & 7);
        bf16x4v h;
        h[0] = (short)f2bf(v.x); h[1] = (short)f2bf(v.y);
        h[2] = (short)f2bf(v.z); h[3] = (short)f2bf(v.w);
        *(bf16x4v*)&smem[idx] = h;
        float s = v.x + v.y + v.z + v.w;
#pragma unroll
        for (int m = 1; m <= 32; m <<= 1) s += __shfl_xor(s, m, 64);
        if (l == 0) saux[c] += s;  // unique writer per (sub,it,w): no race
      }
      __syncthreads();
#pragma unroll
      for (int kb = 0; kb < 8; ++kb) {
        int nn = kb * 32 + lg * 8;
        int arow = w * 16 + lr;  // 8 waves x 16 rows = 128
        bf16x8 fa = *(const bf16x8*)&smem[arow * 256 + (((nn >> 3) ^ (arow & 15)) << 3)];
        bf16x8 fb[8];
#pragma unroll
        for (int bt = 0; bt < 8; ++bt) {
          int drow = bt * 16 + lr;
          fb[bt] = *(const bf16x8*)&smem[drow * 256 + (((nn >> 3) ^ (drow & 15)) << 3)];
        }
#pragma unroll
        for (int bt = 0; bt < 8; ++bt)
          acc[bt] = __builtin_amdgcn_mfma_f32_16x16x32_bf16(fa, fb[bt], acc[bt], 0, 0, 0);
      }
      __syncthreads();  // MFMA reads done before next sub-chunk overwrites smem
    }
    if (t < NC) mpart[(size_t)bid * NC + t] = saux[t];
    u16* gp = Gpartb + ((size_t)bid << 14);
#pragma unroll
    for (int bt = 0; bt < 8; ++bt)
#pragma unroll
      for (int r = 0; r < 4; ++r) {
        int cr = w * 16 + lg * 4 + r;  // C/D: row=(lane>>4)*4+reg
        int d = bt * 16 + lr;          //      col=lane&15
        gp[cr * NC + d] = f2bf(acc[bt][r]);
      }
  } else {
    // ---- weighted q-Gram over one 512-p half (4 chunks of 128 p, pipelined) ----
    int bid2 = bid - 100;
    if (bid2 < 2) {  // zero out (640 floats) for k_wndot's atomic-free... plain stores need no zero,
      int o = bid2 * 512 + t;  // but R6's k_wndot used atomicAdd? No: plain store. Kept harmless.
      if (o < 64 * NWAYS) out[o] = 0.f;
    }
    int b = bid2 >> 1, half = bid2 & 1;
    u16* traw = smem;          // [c][128p] swizzled
    u16* twgt = smem + 16384;  // w_p-scaled
    const float* base = q + (size_t)b * NC * NHW + half * 512;
    const float* cwb = cw + half * 512;

    float4 v[8];
    auto load_chunk = [&](int chunk) {
#pragma unroll
      for (int it = 0; it < 8; ++it) {
        int idx = it * 512 + t;
        int c = idx >> 5, pos = idx & 31;  // 32 float4 per 128-p row
        v[it] = *(const float4*)(base + (size_t)c * NHW + chunk * 128 + pos * 4);
      }
    };
    auto store_chunk = [&](int chunk) {
#pragma unroll
      for (int it = 0; it < 8; ++it) {
        int idx = it * 512 + t;
        int c = idx >> 5, pos = idx & 31;
        float4 vv = v[it];
        float4 wv = *(const float4*)(cwb + chunk * 128 + pos * 4);
        int nl = pos * 4;
        int off = c * 128 + (((nl >> 3) ^ (c & 15)) << 3) + (nl & 7);
        bf16x4v hr, hw;
        hr[0] = (short)f2bf(vv.x); hr[1] = (short)f2bf(vv.y);
        hr[2] = (short)f2bf(vv.z); hr[3] = (short)f2bf(vv.w);
        hw[0] = (short)f2bf(vv.x * wv.x); hw[1] = (short)f2bf(vv.y * wv.y);
        hw[2] = (short)f2bf(vv.z * wv.z); hw[3] = (short)f2bf(vv.w * wv.w);
        *(bf16x4v*)&traw[off] = hr;
        *(bf16x4v*)&twgt[off] = hw;
        float s = vv.x * vv.x + vv.y * vv.y + vv.z * vv.z + vv.w * vv.w;
#pragma unroll
        for (int m = 1; m <= 16; m <<= 1) s += __shfl_xor(s, m, 64);
        if ((l & 31) == 0) saux[c] += s;  // unique writer per (chunk,c)
      }
    };

    load_chunk(0);
    if (t < NC) saux[t] = 0.f;
    __syncthreads();  // init visible before any +=
    store_chunk(0);
    __syncthreads();

    f32x4 acc[8];
#pragma unroll
    for (int bt = 0; bt < 8; ++bt) acc[bt] = (f32x4){0.f, 0.f, 0.f, 0.f};
#pragma unroll 1
    for (int chunk = 0; chunk < 4; ++chunk) {
      if (chunk < 3) load_chunk(chunk + 1);  // issue-early: HBM hides under MFMA
#pragma unroll
      for (int kb = 0; kb < 4; ++kb) {
        int nn = kb * 32 + lg * 8;
        int arow = w * 16 + lr;
        bf16x8 fa = *(const bf16x8*)&twgt[arow * 128 + (((nn >> 3) ^ (arow & 15)) << 3)];
        bf16x8 fb[8];
#pragma unroll
        for (int bt = 0; bt < 8; ++bt) {
          int drow = bt * 16 + lr;
          fb[bt] = *(const bf16x8*)&traw[drow * 128 + (((nn >> 3) ^ (drow & 15)) << 3)];
        }
#pragma unroll
        for (int bt = 0; bt < 8; ++bt)
          acc[bt] = __builtin_amdgcn_mfma_f32_16x16x32_bf16(fa, fb[bt], acc[bt], 0, 0, 0);
      }
      __syncthreads();
      if (chunk < 3) { store_chunk(chunk + 1); __syncthreads(); }
    }

    if (t < NC) ss[(size_t)(half * 64 + b) * NC + t] = saux[t];
    u16* wb = Wrawb + ((size_t)(half * 64 + b) << 14);
#pragma unroll
    for (int bt = 0; bt < 8; ++bt)
#pragma unroll
      for (int r = 0; r < 4; ++r) {
        int cr = w * 16 + lg * 4 + r;
        int d = bt * 16 + lr;
        wb[cr * NC + d] = f2bf(acc[bt][r]);
      }
  }
}

// ---------------- Kernel 2: reduce 10 Gram partials -> bf16 cov ----------------
// grid = 10 j * 16 rowgroups of 8 rows ; block 256 (each thread: 4 consecutive d)
__global__ __launch_bounds__(256) void k_fin(const u16* __restrict__ Gpartb,
                                             const float* __restrict__ mpart,
                                             u16* __restrict__ covb) {
  __shared__ float msd[NC];
  int j = blockIdx.x >> 4, rg = blockIdx.x & 15;
  int t = threadIdx.x;
  if (t < NC) {
    float s = 0.f;
#pragma unroll
    for (int k = 0; k < 10; ++k) s += mpart[(size_t)(j * 10 + k) * NC + t];
    msd[t] = s;
  }
  __syncthreads();
  int e = rg * 1024 + t * 4;  // 8 rows x 128 cols per block
  int c = e >> 7, d0 = e & 127;
  float g[4] = {0.f, 0.f, 0.f, 0.f};
#pragma unroll
  for (int k = 0; k < 10; ++k) {
    bf16x4v v = *(const bf16x4v*)(Gpartb + (((size_t)(j * 10 + k)) << 14) + e);
#pragma unroll
    for (int r = 0; r < 4; ++r) g[r] += bf2f((u16)v[r]);
  }
  bf16x4v o;
#pragma unroll
  for (int r = 0; r < 4; ++r)
    o[r] = (short)f2bf((g[r] - msd[c] * msd[d0 + r] * (1.0f / 5120.0f)) * (1.0f / 5119.0f));
  *(bf16x4v*)(covb + (((size_t)j) << 14) + e) = o;
}

// ---------------- Kernel 3: Wn chunk in registers, dot with all 10 covs ----------------
// grid = 64 b * 4 rowgroups of 32 rows ; block 256 (16 consecutive elems/thread)
__global__ __launch_bounds__(256) void k_wndot(const u16* __restrict__ Wrawb,
                                               const float* __restrict__ ss,
                                               const u16* __restrict__ covb,
                                               float* __restrict__ out) {
  __shared__ float rnl[NC];
  __shared__ float red[4 * NWAYS];
  int b = blockIdx.x >> 2, rg = blockIdx.x & 3;
  int t = threadIdx.x;
  int w = t >> 6, l = t & 63;
  if (t < NC) {
    float s = ss[(size_t)b * NC + t] + ss[(size_t)(64 + b) * NC + t];
    rnl[t] = rsqrtf(s);
  }
  __syncthreads();
  int e = rg * 4096 + t * 16;  // 32 rows x 128 cols per block
  int c = e >> 7, d0 = e & 127;
  float wn[16];
#pragma unroll
  for (int k = 0; k < 16; ++k) wn[k] = 0.f;
#pragma unroll
  for (int qr = 0; qr < 2; ++qr) {
    const u16* src = Wrawb + (((size_t)(qr * 64 + b)) << 14) + e;
    bf16x8 v0 = *(const bf16x8*)src;
    bf16x8 v1 = *(const bf16x8*)(src + 8);
#pragma unroll
    for (int k = 0; k < 8; ++k) { wn[k] += bf2f((u16)v0[k]); wn[8 + k] += bf2f((u16)v1[k]); }
  }
  float rc = rnl[c];
#pragma unroll
  for (int k = 0; k < 16; ++k) wn[k] *= rc * rnl[d0 + k];

  float acc[NWAYS];
#pragma unroll
  for (int j = 0; j < NWAYS; ++j) {
    const u16* cj = covb + ((size_t)j << 14) + e;
    bf16x8 c0 = *(const bf16x8*)cj;
    bf16x8 c1 = *(const bf16x8*)(cj + 8);
    float s = 0.f;
#pragma unroll
    for (int k = 0; k < 8; ++k) s += wn[k] * bf2f((u16)c0[k]) + wn[8 + k] * bf2f((u16)c1[k]);
    acc[j] = s;
  }
#pragma unroll
  for (int j = 0; j < NWAYS; ++j)
#pragma unroll
    for (int m = 1; m <= 32; m <<= 1) acc[j] += __shfl_xor(acc[j], m, 64);
  if (l == 0)
#pragma unroll
    for (int j = 0; j < NWAYS; ++j) red[w * NWAYS + j] = acc[j];
  __syncthreads();
  if (t < NWAYS)
    atomicAdd(&out[b * NWAYS + t],
              red[t] + red[NWAYS + t] + red[2 * NWAYS + t] + red[3 * NWAYS + t]);
}

extern "C" void kernel_launch(void* const* d_in, const int* in_sizes, int n_in,
                              void* d_out, int out_size, void* d_ws, size_t ws_size,
                              hipStream_t stream) {
  (void)in_sizes; (void)n_in; (void)out_size; (void)ws_size;
  const float* q = (const float*)d_in[0];
  const float* sup = (const float*)d_in[1];
  const float* cw = (const float*)d_in[2];
  float* out = (float*)d_out;

  char* p = (char*)d_ws;
  u16* Gpartb = (u16*)p;    p += (size_t)100 * 16384 * 2;  // 3.28 MB
  float* mpart = (float*)p; p += (size_t)100 * 128 * 4;
  u16* covb = (u16*)p;      p += (size_t)10 * 16384 * 2;
  u16* Wrawb = (u16*)p;     p += (size_t)128 * 16384 * 2;  // 4.19 MB
  float* ssb = (float*)p;

  k_phase1<<<228, 512, 0, stream>>>(sup, q, cw, Gpartb, mpart, Wrawb, ssb, out);
  k_fin<<<160, 256, 0, stream>>>(Gpartb, mpart, covb);
  k_wndot<<<256, 256, 0, stream>>>(Wrawb, ssb, covb, out);
}

// Round 13
// 29.734 us; speedup vs baseline: 6.4855x; 1.2129x over previous
//
#include <hip/hip_runtime.h>

typedef unsigned short u16;
typedef unsigned int u32;
typedef __attribute__((ext_vector_type(8))) short bf16x8;
typedef __attribute__((ext_vector_type(4))) short bf16x4v;
typedef __attribute__((ext_vector_type(4))) float f32x4;

#define NWAYS 10
#define NC 128
#define NHW 1024

__device__ __forceinline__ u16 f2bf(float f) {
  u32 u = __builtin_bit_cast(u32, f);
  return (u16)((u + 0x7fffu + ((u >> 16) & 1u)) >> 16);  // RNE
}
__device__ __forceinline__ float bf2f(u16 h) {
  u32 u = ((u32)h) << 16;
  return __builtin_bit_cast(float, u);
}

// ---------------- Kernel 1: fused support-Gram + weighted q-Gram, both pipelined ----------------
// blocks 0..99    : Gpartb[j*10+cid] = bf16 Gram of a 512-n support chunk, 4x128-n pipelined
//                   (reg-prefetch next chunk during MFMA) ; mpart = f32 rowsums over 512 n
// blocks 100..227 : Wrawb[half*64+b] = bf16 sum_p w_p q_c q_d over 512-p half (4-chunk pipeline) ;
//                   ss[half*64+b] = sum q_c^2
// block = 512 threads (8 waves)
__global__ __launch_bounds__(512) void k_phase1(const float* __restrict__ sup,
                                                const float* __restrict__ q,
                                                const float* __restrict__ cw,
                                                u16* __restrict__ Gpartb,
                                                float* __restrict__ mpart,
                                                u16* __restrict__ Wrawb,
                                                float* __restrict__ ss,
                                                float* __restrict__ out) {
  __shared__ u16 smem[NC * 256];  // 64 KiB (q-gram uses both halves; Gram uses first 32 KiB)
  __shared__ float saux[NC];
  int bid = blockIdx.x;
  int t = threadIdx.x;
  int w = t >> 6, l = t & 63, lr = l & 15, lg = l >> 4;

  if (bid < 100) {
    // ---- support Gram over one 512-n chunk: 4 pipelined chunks of 128 n ----
    int j = bid / 10, cid = bid % 10;
    int shot = cid >> 1, p0 = (cid & 1) * 512;
    const float* base = sup + ((size_t)(j * 5 + shot) * NC) * NHW + p0;
    u16* traw = smem;  // [c][128n] swizzled, 32 KiB

    float4 v[8];
    auto load_chunk = [&](int chunk) {
#pragma unroll
      for (int it = 0; it < 8; ++it) {
        int idx = it * 512 + t;
        int c = idx >> 5, pos = idx & 31;  // 32 float4 per 128-n row
        v[it] = *(const float4*)(base + (size_t)c * NHW + chunk * 128 + pos * 4);
      }
    };
    auto store_chunk = [&](int chunk) {
      (void)chunk;
#pragma unroll
      for (int it = 0; it < 8; ++it) {
        int idx = it * 512 + t;
        int c = idx >> 5, pos = idx & 31;
        float4 vv = v[it];
        int nl = pos * 4;
        int off = c * 128 + (((nl >> 3) ^ (c & 15)) << 3) + (nl & 7);
        bf16x4v hr;
        hr[0] = (short)f2bf(vv.x); hr[1] = (short)f2bf(vv.y);
        hr[2] = (short)f2bf(vv.z); hr[3] = (short)f2bf(vv.w);
        *(bf16x4v*)&traw[off] = hr;
        float s = vv.x + vv.y + vv.z + vv.w;
#pragma unroll
        for (int m = 1; m <= 16; m <<= 1) s += __shfl_xor(s, m, 64);
        if ((l & 31) == 0) saux[c] += s;  // unique writer per (chunk,c)
      }
    };

    load_chunk(0);
    if (t < NC) saux[t] = 0.f;
    __syncthreads();  // init visible before any +=
    store_chunk(0);
    __syncthreads();

    f32x4 acc[8];
#pragma unroll
    for (int bt = 0; bt < 8; ++bt) acc[bt] = (f32x4){0.f, 0.f, 0.f, 0.f};
#pragma unroll 1
    for (int chunk = 0; chunk < 4; ++chunk) {
      if (chunk < 3) load_chunk(chunk + 1);  // issue-early: HBM hides under MFMA
#pragma unroll
      for (int kb = 0; kb < 4; ++kb) {
        int nn = kb * 32 + lg * 8;
        int arow = w * 16 + lr;  // 8 waves x 16 rows = 128
        bf16x8 fa = *(const bf16x8*)&traw[arow * 128 + (((nn >> 3) ^ (arow & 15)) << 3)];
        bf16x8 fb[8];
#pragma unroll
        for (int bt = 0; bt < 8; ++bt) {
          int drow = bt * 16 + lr;
          fb[bt] = *(const bf16x8*)&traw[drow * 128 + (((nn >> 3) ^ (drow & 15)) << 3)];
        }
#pragma unroll
        for (int bt = 0; bt < 8; ++bt)
          acc[bt] = __builtin_amdgcn_mfma_f32_16x16x32_bf16(fa, fb[bt], acc[bt], 0, 0, 0);
      }
      __syncthreads();
      if (chunk < 3) { store_chunk(chunk + 1); __syncthreads(); }
    }

    if (t < NC) mpart[(size_t)bid * NC + t] = saux[t];
    u16* gp = Gpartb + ((size_t)bid << 14);
#pragma unroll
    for (int bt = 0; bt < 8; ++bt)
#pragma unroll
      for (int r = 0; r < 4; ++r) {
        int cr = w * 16 + lg * 4 + r;  // C/D: row=(lane>>4)*4+reg
        int d = bt * 16 + lr;          //      col=lane&15
        gp[cr * NC + d] = f2bf(acc[bt][r]);
      }
  } else {
    // ---- weighted q-Gram over one 512-p half (4 chunks of 128 p, pipelined) ----
    int bid2 = bid - 100;
    if (bid2 < 2) {  // zero out (640 floats) for k_wndot's atomicAdd
      int o = bid2 * 512 + t;
      if (o < 64 * NWAYS) out[o] = 0.f;
    }
    int b = bid2 >> 1, half = bid2 & 1;
    u16* traw = smem;          // [c][128p] swizzled
    u16* twgt = smem + 16384;  // w_p-scaled
    const float* base = q + (size_t)b * NC * NHW + half * 512;
    const float* cwb = cw + half * 512;

    float4 v[8];
    auto load_chunk = [&](int chunk) {
#pragma unroll
      for (int it = 0; it < 8; ++it) {
        int idx = it * 512 + t;
        int c = idx >> 5, pos = idx & 31;  // 32 float4 per 128-p row
        v[it] = *(const float4*)(base + (size_t)c * NHW + chunk * 128 + pos * 4);
      }
    };
    auto store_chunk = [&](int chunk) {
#pragma unroll
      for (int it = 0; it < 8; ++it) {
        int idx = it * 512 + t;
        int c = idx >> 5, pos = idx & 31;
        float4 vv = v[it];
        float4 wv = *(const float4*)(cwb + chunk * 128 + pos * 4);
        int nl = pos * 4;
        int off = c * 128 + (((nl >> 3) ^ (c & 15)) << 3) + (nl & 7);
        bf16x4v hr, hw;
        hr[0] = (short)f2bf(vv.x); hr[1] = (short)f2bf(vv.y);
        hr[2] = (short)f2bf(vv.z); hr[3] = (short)f2bf(vv.w);
        hw[0] = (short)f2bf(vv.x * wv.x); hw[1] = (short)f2bf(vv.y * wv.y);
        hw[2] = (short)f2bf(vv.z * wv.z); hw[3] = (short)f2bf(vv.w * wv.w);
        *(bf16x4v*)&traw[off] = hr;
        *(bf16x4v*)&twgt[off] = hw;
        float s = vv.x * vv.x + vv.y * vv.y + vv.z * vv.z + vv.w * vv.w;
#pragma unroll
        for (int m = 1; m <= 16; m <<= 1) s += __shfl_xor(s, m, 64);
        if ((l & 31) == 0) saux[c] += s;  // unique writer per (chunk,c)
      }
    };

    load_chunk(0);
    if (t < NC) saux[t] = 0.f;
    __syncthreads();  // init visible before any +=
    store_chunk(0);
    __syncthreads();

    f32x4 acc[8];
#pragma unroll
    for (int bt = 0; bt < 8; ++bt) acc[bt] = (f32x4){0.f, 0.f, 0.f, 0.f};
#pragma unroll 1
    for (int chunk = 0; chunk < 4; ++chunk) {
      if (chunk < 3) load_chunk(chunk + 1);  // issue-early: HBM hides under MFMA
#pragma unroll
      for (int kb = 0; kb < 4; ++kb) {
        int nn = kb * 32 + lg * 8;
        int arow = w * 16 + lr;
        bf16x8 fa = *(const bf16x8*)&twgt[arow * 128 + (((nn >> 3) ^ (arow & 15)) << 3)];
        bf16x8 fb[8];
#pragma unroll
        for (int bt = 0; bt < 8; ++bt) {
          int drow = bt * 16 + lr;
          fb[bt] = *(const bf16x8*)&traw[drow * 128 + (((nn >> 3) ^ (drow & 15)) << 3)];
        }
#pragma unroll
        for (int bt = 0; bt < 8; ++bt)
          acc[bt] = __builtin_amdgcn_mfma_f32_16x16x32_bf16(fa, fb[bt], acc[bt], 0, 0, 0);
      }
      __syncthreads();
      if (chunk < 3) { store_chunk(chunk + 1); __syncthreads(); }
    }

    if (t < NC) ss[(size_t)(half * 64 + b) * NC + t] = saux[t];
    u16* wb = Wrawb + ((size_t)(half * 64 + b) << 14);
#pragma unroll
    for (int bt = 0; bt < 8; ++bt)
#pragma unroll
      for (int r = 0; r < 4; ++r) {
        int cr = w * 16 + lg * 4 + r;
        int d = bt * 16 + lr;
        wb[cr * NC + d] = f2bf(acc[bt][r]);
      }
  }
}

// ---------------- Kernel 2: reduce 10 Gram partials -> bf16 cov ----------------
// grid = 10 j * 16 rowgroups of 8 rows ; block 256 (each thread: 4 consecutive d)
__global__ __launch_bounds__(256) void k_fin(const u16* __restrict__ Gpartb,
                                             const float* __restrict__ mpart,
                                             u16* __restrict__ covb) {
  __shared__ float msd[NC];
  int j = blockIdx.x >> 4, rg = blockIdx.x & 15;
  int t = threadIdx.x;
  if (t < NC) {
    float s = 0.f;
#pragma unroll
    for (int k = 0; k < 10; ++k) s += mpart[(size_t)(j * 10 + k) * NC + t];
    msd[t] = s;
  }
  __syncthreads();
  int e = rg * 1024 + t * 4;  // 8 rows x 128 cols per block
  int c = e >> 7, d0 = e & 127;
  float g[4] = {0.f, 0.f, 0.f, 0.f};
#pragma unroll
  for (int k = 0; k < 10; ++k) {
    bf16x4v v = *(const bf16x4v*)(Gpartb + (((size_t)(j * 10 + k)) << 14) + e);
#pragma unroll
    for (int r = 0; r < 4; ++r) g[r] += bf2f((u16)v[r]);
  }
  bf16x4v o;
#pragma unroll
  for (int r = 0; r < 4; ++r)
    o[r] = (short)f2bf((g[r] - msd[c] * msd[d0 + r] * (1.0f / 5120.0f)) * (1.0f / 5119.0f));
  *(bf16x4v*)(covb + (((size_t)j) << 14) + e) = o;
}

// ---------------- Kernel 3: Wn chunk in registers, dot with all 10 covs ----------------
// grid = 64 b * 4 rowgroups of 32 rows ; block 256 (16 consecutive elems/thread)
__global__ __launch_bounds__(256) void k_wndot(const u16* __restrict__ Wrawb,
                                               const float* __restrict__ ss,
                                               const u16* __restrict__ covb,
                                               float* __restrict__ out) {
  __shared__ float rnl[NC];
  __shared__ float red[4 * NWAYS];
  int b = blockIdx.x >> 2, rg = blockIdx.x & 3;
  int t = threadIdx.x;
  int w = t >> 6, l = t & 63;
  if (t < NC) {
    float s = ss[(size_t)b * NC + t] + ss[(size_t)(64 + b) * NC + t];
    rnl[t] = rsqrtf(s);
  }
  __syncthreads();
  int e = rg * 4096 + t * 16;  // 32 rows x 128 cols per block
  int c = e >> 7, d0 = e & 127;
  float wn[16];
#pragma unroll
  for (int k = 0; k < 16; ++k) wn[k] = 0.f;
#pragma unroll
  for (int qr = 0; qr < 2; ++qr) {
    const u16* src = Wrawb + (((size_t)(qr * 64 + b)) << 14) + e;
    bf16x8 v0 = *(const bf16x8*)src;
    bf16x8 v1 = *(const bf16x8*)(src + 8);
#pragma unroll
    for (int k = 0; k < 8; ++k) { wn[k] += bf2f((u16)v0[k]); wn[8 + k] += bf2f((u16)v1[k]); }
  }
  float rc = rnl[c];
#pragma unroll
  for (int k = 0; k < 16; ++k) wn[k] *= rc * rnl[d0 + k];

  float acc[NWAYS];
#pragma unroll
  for (int j = 0; j < NWAYS; ++j) {
    const u16* cj = covb + ((size_t)j << 14) + e;
    bf16x8 c0 = *(const bf16x8*)cj;
    bf16x8 c1 = *(const bf16x8*)(cj + 8);
    float s = 0.f;
#pragma unroll
    for (int k = 0; k < 8; ++k) s += wn[k] * bf2f((u16)c0[k]) + wn[8 + k] * bf2f((u16)c1[k]);
    acc[j] = s;
  }
#pragma unroll
  for (int j = 0; j < NWAYS; ++j)
#pragma unroll
    for (int m = 1; m <= 32; m <<= 1) acc[j] += __shfl_xor(acc[j], m, 64);
  if (l == 0)
#pragma unroll
    for (int j = 0; j < NWAYS; ++j) red[w * NWAYS + j] = acc[j];
  __syncthreads();
  if (t < NWAYS)
    atomicAdd(&out[b * NWAYS + t],
              red[t] + red[NWAYS + t] + red[2 * NWAYS + t] + red[3 * NWAYS + t]);
}

extern "C" void kernel_launch(void* const* d_in, const int* in_sizes, int n_in,
                              void* d_out, int out_size, void* d_ws, size_t ws_size,
                              hipStream_t stream) {
  (void)in_sizes; (void)n_in; (void)out_size; (void)ws_size;
  const float* q = (const float*)d_in[0];
  const float* sup = (const float*)d_in[1];
  const float* cw = (const float*)d_in[2];
  float* out = (float*)d_out;

  char* p = (char*)d_ws;
  u16* Gpartb = (u16*)p;    p += (size_t)100 * 16384 * 2;  // 3.28 MB
  float* mpart = (float*)p; p += (size_t)100 * 128 * 4;
  u16* covb = (u16*)p;      p += (size_t)10 * 16384 * 2;
  u16* Wrawb = (u16*)p;     p += (size_t)128 * 16384 * 2;  // 4.19 MB
  float* ssb = (float*)p;

  k_phase1<<<228, 512, 0, stream>>>(sup, q, cw, Gpartb, mpart, Wrawb, ssb, out);
  k_fin<<<160, 256, 0, stream>>>(Gpartb, mpart, covb);
  k_wndot<<<256, 256, 0, stream>>>(Wrawb, ssb, covb, out);
}